// Round 1
// baseline (3381.305 us; speedup 1.0000x reference)
//
#include <hip/hip_runtime.h>

#define BB   32
#define TT   2048
#define HH   256
#define G3   768      // 3*H
#define NVOC 18       // vocab rows (V+2)
#define NOUT 17       // head outputs (V+1)
#define LOGITS_ELEMS ((size_t)BB * TT * NOUT)

typedef _Float16 f16x8 __attribute__((ext_vector_type(8)));
typedef float    f32x4 __attribute__((ext_vector_type(4)));

__device__ __forceinline__ float bf1(unsigned short u){
  union{unsigned int i; float f;} v; v.i = ((unsigned int)u) << 16; return v.f;
}
__device__ __forceinline__ unsigned short f2bf(float f){
  union{float f; unsigned int i;} v; v.f = f;
  unsigned int lsb = (v.i >> 16) & 1u;
  v.i += 0x7fffu + lsb;               // round-to-nearest-even
  return (unsigned short)(v.i >> 16);
}
__device__ __forceinline__ float bflo(unsigned int u){
  union{unsigned int i; float f;} v; v.i = u << 16; return v.f;
}
__device__ __forceinline__ float bfhi(unsigned int u){
  union{unsigned int i; float f;} v; v.i = u & 0xffff0000u; return v.f;
}

__device__ __forceinline__ float ld1(const float* p, size_t i){ return p[i]; }
__device__ __forceinline__ float ld1(const unsigned short* p, size_t i){ return bf1(p[i]); }

// Device-side dtype detection: W_ih ~ uniform(-1/16,1/16). If the buffer is
// f32, low-half words decode as bf16 with random exponents -> some |v|>0.25.
__device__ __forceinline__ bool detect_f32(const void* W_ih_raw){
  const unsigned short* u = (const unsigned short*)W_ih_raw;
  bool big = false;
  #pragma unroll
  for (int i = 0; i < 64; i++){
    float v = bf1(u[i]);
    big |= !(v >= -0.25f && v <= 0.25f);
  }
  return big;
}

// ---------------------------------------------------------------------------
// k_prep: pack W_hh into per-lane MFMA B-fragment layout for k_scan.
// k_scan: wave w (of 8) owns N-tiles {6w..6w+5} (cols 96w..96w+95), 8 K-tiles.
// B-frag layout (v_mfma_f32_16x16x32_f16): lane l holds
//   B[k = 32*k0 + 8*(l>>4) + j][col = 16*tile + (l&15)],  j = 0..7.
// Flat slot s = ((w*6+ti)*8 + k0)*64 + l ; Wp[s*8 + j] as above.
// ---------------------------------------------------------------------------
template<typename T>
__device__ __forceinline__ void prep_body(const T* W_hh, _Float16* Wp){
  int s  = blockIdx.x * 256 + threadIdx.x;   // 0..24575
  int l  = s & 63;
  int k0 = (s >> 6) & 7;
  int t2 = s >> 9;                           // 0..47 = w*6 + ti
  int row0 = 32*k0 + 8*(l >> 4);
  int col  = 16*t2 + (l & 15);               // = 96w + 16ti + c
  f16x8 v;
  #pragma unroll
  for (int i2 = 0; i2 < 8; i2++)
    v[i2] = (_Float16)ld1(W_hh, (size_t)(row0 + i2) * G3 + col);
  ((f16x8*)Wp)[s] = v;
}

__global__ __launch_bounds__(256) void k_prep(
    const void* __restrict__ W_hh, const void* __restrict__ W_ih,
    _Float16* __restrict__ Wp)
{
  if (detect_f32(W_ih)) prep_body<float>((const float*)W_hh, Wp);
  else                  prep_body<unsigned short>((const unsigned short*)W_hh, Wp);
}

// ---------------------------------------------------------------------------
// k_proj: proj[v][j] = b_ih[j] + sum_k embed[v][k]*W_ih[k][j]. Block = one v,
// 768 threads, coalesced W_ih reads. Block 0 also converts b_hh -> f32 bb[].
// ---------------------------------------------------------------------------
template<typename T>
__device__ __forceinline__ void proj_body(const T* embed, const T* W_ih,
                                          const T* b_ih, const T* b_hh,
                                          float* proj, float* bb){
  __shared__ float s_e[HH];
  int v = blockIdx.x, j = threadIdx.x;
  if (j < HH) s_e[j] = ld1(embed, (size_t)v * HH + j);
  if (v == 0) bb[j] = ld1(b_hh, (size_t)j);
  __syncthreads();
  float acc = ld1(b_ih, (size_t)j);
  #pragma unroll 8
  for (int k = 0; k < HH; k++)
    acc += s_e[k] * ld1(W_ih, (size_t)k * G3 + j);
  proj[(size_t)v * G3 + j] = acc;
}

__global__ __launch_bounds__(768) void k_proj(
    const void* __restrict__ embed, const void* __restrict__ W_ih,
    const void* __restrict__ b_ih, const void* __restrict__ b_hh,
    float* __restrict__ proj, float* __restrict__ bb)
{
  if (detect_f32(W_ih))
    proj_body<float>((const float*)embed, (const float*)W_ih,
                     (const float*)b_ih, (const float*)b_hh, proj, bb);
  else
    proj_body<unsigned short>((const unsigned short*)embed,
                              (const unsigned short*)W_ih,
                              (const unsigned short*)b_ih,
                              (const unsigned short*)b_hh, proj, bb);
}

// ---------------------------------------------------------------------------
// k_scan: GRU scan on the matrix pipe. One block per batch element,
// 512 threads = 8 waves. Per step:
//   gh = h @ W_hh + b_hh via v_mfma_f32_16x16x32_f16 with h broadcast into
//   all 16 A-rows (rows identical -> acc reg 0 on every lane is a valid
//   D[*, col=lane&15] value). Wave w owns cols [96w, 96w+96): 6 tiles x
//   8 chained K-steps, W_hh register-resident (48 f16x8 = 192 VGPRs).
//   A-frag read: 8x ds_read_b128/wave, 4 unique 16B lines (conflict-free
//   broadcast) vs 16 b128/thread in the fdot2 version.
//   Gates: thread j<256 reads r/z/n from s_gh (bias pre-folded into acc).
// ---------------------------------------------------------------------------
__global__ __launch_bounds__(512, 2) void k_scan(
    const int*      __restrict__ tokens,
    const _Float16* __restrict__ Wp,     // prepped weights
    const float*    __restrict__ bb,     // b_hh as f32
    const void*     __restrict__ W_ih,   // dtype detection (betas store)
    const float*    __restrict__ proj,
    unsigned short* __restrict__ outs,   // [B,T,H] bf16 scratch
    void*           __restrict__ d_out_base)
{
  __shared__ float s_proj[NVOC * G3];            // 55296 B
  __shared__ __align__(16) _Float16 s_h[HH];     // 512 B f16 hidden state
  __shared__ float s_gh[G3];                     // 3072 B gh scatter buffer

  const bool f32m = detect_f32(W_ih);
  const int b = blockIdx.x;
  const int j = threadIdx.x;       // 0..511
  const int w = j >> 6;            // wave 0..7
  const int l = j & 63;
  const int g = l >> 4;            // 16-lane group 0..3
  const int c = l & 15;

  // stage proj (vectorized; 13824 f32 = 3456 float4)
  for (int i = j; i < NVOC * G3 / 4; i += 512)
    ((float4*)s_proj)[i] = ((const float4*)proj)[i];

  // register-resident B-fragments: wB[ti*8 + k0]
  f16x8 wB[48];
  {
    const f16x8* wpp = (const f16x8*)Wp + (size_t)w * 48 * 64 + l;
    #pragma unroll
    for (int i = 0; i < 48; i++) wB[i] = wpp[(size_t)i * 64];
  }
  // b_hh folded into acc init: bh[ti] = bb[col(tile 6w+ti, lane col c)]
  const float bh0 = bb[96*w +  0 + c];
  const float bh1 = bb[96*w + 16 + c];
  const float bh2 = bb[96*w + 32 + c];
  const float bh3 = bb[96*w + 48 + c];
  const float bh4 = bb[96*w + 64 + c];
  const float bh5 = bb[96*w + 80 + c];

  if (j < HH) s_h[j] = (_Float16)0.f;

  float h_old = 0.f;               // thread j<256 owns h[j]
  const int* tptr = tokens + (size_t)b * TT;
  int tok = 0;
  unsigned short* orow   = outs + (size_t)b * TT * HH + j;
  unsigned short* brow_b = (unsigned short*)d_out_base + LOGITS_ELEMS
                           + (size_t)b * TT * HH + j;
  float*          brow_f = (float*)d_out_base + LOGITS_ELEMS
                           + (size_t)b * TT * HH + j;
  if (j < HH) tok = tptr[0];

  __syncthreads();

  const f16x8* hp8 = (const f16x8*)s_h;

  for (int t = 0; t < TT; t++) {
    int tok_next = 0;
    if (j < HH) tok_next = (t + 1 < TT) ? tptr[t + 1] : 0;

    f32x4 acc0 = {bh0, bh0, bh0, bh0};
    f32x4 acc1 = {bh1, bh1, bh1, bh1};
    f32x4 acc2 = {bh2, bh2, bh2, bh2};
    f32x4 acc3 = {bh3, bh3, bh3, bh3};
    f32x4 acc4 = {bh4, bh4, bh4, bh4};
    f32x4 acc5 = {bh5, bh5, bh5, bh5};

    // A-frag: lane l needs h[32*k0 + 8*g .. +8] (row = c is don't-care:
    // all rows identical). 4 unique 16B lines per read -> conflict-free.
    #pragma unroll
    for (int k0 = 0; k0 < 8; k0++) {
      f16x8 af = hp8[4*k0 + g];
      acc0 = __builtin_amdgcn_mfma_f32_16x16x32_f16(af, wB[ 0 + k0], acc0, 0, 0, 0);
      acc1 = __builtin_amdgcn_mfma_f32_16x16x32_f16(af, wB[ 8 + k0], acc1, 0, 0, 0);
      acc2 = __builtin_amdgcn_mfma_f32_16x16x32_f16(af, wB[16 + k0], acc2, 0, 0, 0);
      acc3 = __builtin_amdgcn_mfma_f32_16x16x32_f16(af, wB[24 + k0], acc3, 0, 0, 0);
      acc4 = __builtin_amdgcn_mfma_f32_16x16x32_f16(af, wB[32 + k0], acc4, 0, 0, 0);
      acc5 = __builtin_amdgcn_mfma_f32_16x16x32_f16(af, wB[40 + k0], acc5, 0, 0, 0);
    }
    // D layout: col = lane&15, row = 4g+reg; all rows equal -> reg 0 valid on
    // every lane. One b32 write covers 4 tiles (lane group g -> tile 6w+g):
    // word idx 96w + 16g + c = 96w + l  -> 64 consecutive words, conflict-free.
    {
      float v1 = (g == 0) ? acc0[0] : (g == 1) ? acc1[0]
               : (g == 2) ? acc2[0] : acc3[0];
      s_gh[96*w + l] = v1;
      if (l < 32) {
        float v2 = (g == 0) ? acc4[0] : acc5[0];
        s_gh[96*w + 64 + l] = v2;
      }
    }
    __syncthreads();

    if (j < HH) {
      const float* pj = s_proj + tok * G3;
      float ghr = s_gh[j];
      float ghz = s_gh[HH + j];
      float ghn = s_gh[2*HH + j];
      float r = 1.f / (1.f + __expf(-(pj[j] + ghr)));
      float z = 1.f / (1.f + __expf(-(pj[HH + j] + ghz)));
      if (f32m) brow_f[(size_t)t * HH] = z;       // beta store
      else      brow_b[(size_t)t * HH] = f2bf(z);
      float x = pj[2*HH + j] + r * ghn;           // i_n + r*(h_n incl bias)
      x = fminf(fmaxf(x, -15.f), 15.f);
      float e = __expf(2.f * x);
      float n = (e - 1.f) / (e + 1.f);            // tanh
      float hn = (1.f - z) * n + z * h_old;
      h_old = hn;
      s_h[j] = (_Float16)hn;                      // publish h for next step
      orow[(size_t)t * HH] = f2bf(hn);
      tok = tok_next;
    }
    __syncthreads();
  }
}

// ---------------------------------------------------------------------------
// k_head: logits = outs @ W_head + b_head
// ---------------------------------------------------------------------------
template<typename T>
__device__ __forceinline__ void stage_head(const T* W_head, const T* b_head,
                                           float* s_w, float* s_b, int tid){
  for (int i = tid; i < NOUT * HH; i += 256) {
    int o = i / HH, k = i - o * HH;
    s_w[i] = ld1(W_head, (size_t)k * NOUT + o);
  }
  if (tid < NOUT) s_b[tid] = ld1(b_head, (size_t)tid);
}

__global__ __launch_bounds__(256) void k_head(
    const unsigned short* __restrict__ outs,
    const void* __restrict__ W_head,
    const void* __restrict__ b_head,
    const void* __restrict__ W_ih,
    void* __restrict__ logits_out)
{
  __shared__ float s_w[NOUT * HH];
  __shared__ float s_b[NOUT];
  const bool f32m = detect_f32(W_ih);
  const int tid = threadIdx.x;

  if (f32m) stage_head<float>((const float*)W_head, (const float*)b_head,
                              s_w, s_b, tid);
  else      stage_head<unsigned short>((const unsigned short*)W_head,
                                       (const unsigned short*)b_head,
                                       s_w, s_b, tid);
  __syncthreads();

  size_t gid = (size_t)blockIdx.x * 256 + tid;
  if (gid >= LOGITS_ELEMS) return;
  int o = (int)(gid % NOUT);
  size_t row = gid / NOUT;

  const uint4* xp = (const uint4*)(outs + row * HH);
  const float* wv = s_w + o * HH;
  float a0 = 0.f, a1 = 0.f, a2 = 0.f, a3 = 0.f;
  #pragma unroll 8
  for (int kk = 0; kk < 32; kk++) {
    uint4 u = xp[kk];
    int kb = kk * 8;
    a0 += bflo(u.x) * wv[kb+0] + bfhi(u.x) * wv[kb+1];
    a1 += bflo(u.y) * wv[kb+2] + bfhi(u.y) * wv[kb+3];
    a2 += bflo(u.z) * wv[kb+4] + bfhi(u.z) * wv[kb+5];
    a3 += bflo(u.w) * wv[kb+6] + bfhi(u.w) * wv[kb+7];
  }
  float val = ((a0 + a1) + (a2 + a3)) + s_b[o];
  if (f32m) ((float*)logits_out)[gid] = val;
  else      ((unsigned short*)logits_out)[gid] = f2bf(val);
}

// ---------------------------------------------------------------------------
extern "C" void kernel_launch(void* const* d_in, const int* in_sizes, int n_in,
                              void* d_out, int out_size, void* d_ws, size_t ws_size,
                              hipStream_t stream)
{
  // inputs: tokens, embed, W_ih, W_hh, b_ih, b_hh, W_head, b_head
  const int* tokens = (const int*)d_in[0];
  const void* embed  = d_in[1];
  const void* W_ih   = d_in[2];
  const void* W_hh   = d_in[3];
  const void* b_ih   = d_in[4];
  const void* b_hh   = d_in[5];
  const void* W_head = d_in[6];
  const void* b_head = d_in[7];

  // workspace layout (16B aligned):
  // proj: 13824 f32 = 55296 B | bb: 768 f32 = 3072 B | Wp: 196608 f16 = 393216 B | outs
  char* ws = (char*)d_ws;
  float*          proj = (float*)ws;
  float*          bb   = (float*)(ws + 55296);
  _Float16*       Wp   = (_Float16*)(ws + 55296 + 3072);
  unsigned short* outs = (unsigned short*)(ws + 55296 + 3072 + 393216);

  k_prep<<<96, 256, 0, stream>>>(W_hh, W_ih, Wp);
  k_proj<<<NVOC, G3, 0, stream>>>(embed, W_ih, b_ih, b_hh, proj, bb);
  k_scan<<<BB, 512, 0, stream>>>(tokens, Wp, bb, W_ih, proj, outs, d_out);
  k_head<<<(int)((LOGITS_ELEMS + 255) / 256), 256, 0, stream>>>(
      outs, W_head, b_head, W_ih, d_out);
}

// Round 2
// 2650.591 us; speedup vs baseline: 1.2757x; 1.2757x over previous
//
#include <hip/hip_runtime.h>

#define BB   32
#define TT   2048
#define HH   256
#define G3   768      // 3*H
#define NVOC 18       // vocab rows (V+2)
#define NOUT 17       // head outputs (V+1)
#define LOGITS_ELEMS ((size_t)BB * TT * NOUT)

typedef _Float16 h2 __attribute__((ext_vector_type(2)));

__device__ __forceinline__ float bf1(unsigned short u){
  union{unsigned int i; float f;} v; v.i = ((unsigned int)u) << 16; return v.f;
}
__device__ __forceinline__ unsigned short f2bf(float f){
  union{float f; unsigned int i;} v; v.f = f;
  unsigned int lsb = (v.i >> 16) & 1u;
  v.i += 0x7fffu + lsb;               // round-to-nearest-even
  return (unsigned short)(v.i >> 16);
}

__device__ __forceinline__ float ld1(const float* p, size_t i){ return p[i]; }
__device__ __forceinline__ float ld1(const unsigned short* p, size_t i){ return bf1(p[i]); }

// Device-side dtype detection: W_ih ~ uniform(-1/16,1/16). If the buffer is
// f32, low-half words decode as bf16 with random exponents -> some |v|>0.25.
__device__ __forceinline__ bool detect_f32(const void* W_ih_raw){
  const unsigned short* u = (const unsigned short*)W_ih_raw;
  bool big = false;
  #pragma unroll
  for (int i = 0; i < 64; i++){
    float v = bf1(u[i]);
    big |= !(v >= -0.25f && v <= 0.25f);
  }
  return big;
}

#if __has_builtin(__builtin_amdgcn_fdot2)
#define FDOT2(a,b,c) __builtin_amdgcn_fdot2((a),(b),(c),false)
#else
#define FDOT2(a,b,c) ((c) + (float)(a).x*(float)(b).x + (float)(a).y*(float)(b).y)
#endif

__device__ __forceinline__ h2 bch2(unsigned int u){ return __builtin_bit_cast(h2, u); }
__device__ __forceinline__ h2 bch2f(float f){ return __builtin_bit_cast(h2, f); }

// pair-swap (lane 2k <-> 2k+1) via DPP quad_perm(1,0,3,2) -- pure VALU,
// avoids the ds_bpermute round-trip __shfl_xor can emit.
__device__ __forceinline__ float pair_swap(float v){
  int i = __builtin_bit_cast(int, v);
  i = __builtin_amdgcn_mov_dpp(i, 0xB1, 0xF, 0xF, true);
  return __builtin_bit_cast(float, i);
}

// raw barrier: LDS-visibility only. Skips __syncthreads()'s vmcnt(0) drain so
// the per-step global stores (outs/betas, never read back in-kernel) stay
// fire-and-forget instead of stalling every iteration.
__device__ __forceinline__ void bar_lds(){
  asm volatile("s_waitcnt lgkmcnt(0)\n\ts_barrier" ::: "memory");
}

// ---------------------------------------------------------------------------
// k_prep: pack W_hh for k_scan's 512-thread triple-ownership layout.
// k_scan thread tid (p=tid>>1, q=tid&1) owns gate outputs {p,256+p,512+p}
// with k in [128q,128q+128). Its register file wreg[g*16+jx] is a float4 of
// 4 h2 k-pairs:  pair c of wreg[g*16+jx] = ( W_hh[k0+2c][col], W_hh[k0+2c+1][col] )
// with k0 = 128q+8jx, col = 256g+p.  Flat: Wp4[(g*16+jx)*512 + tid], so prep
// thread s (grid 96x256 = 24576) writes exactly Wp4[s].
// ---------------------------------------------------------------------------
template<typename T>
__device__ __forceinline__ void prep_body(const T* W_hh, float4* Wp4){
  int s   = blockIdx.x * 256 + threadIdx.x;    // 0..24575
  int tid = s & 511;
  int jg  = s >> 9;                            // 0..47 = g*16+jx
  int p   = tid >> 1, q = tid & 1;
  int g   = jg >> 4,  jx = jg & 15;
  int col = (g << 8) + p;                      // 256g + p
  int k0  = (q << 7) + (jx << 3);              // 128q + 8jx
  float c0, c1, c2, c3;
  #pragma unroll
  for (int c = 0; c < 4; c++){
    h2 pr;
    pr.x = (_Float16)ld1(W_hh, (size_t)(k0 + 2*c    ) * G3 + col);
    pr.y = (_Float16)ld1(W_hh, (size_t)(k0 + 2*c + 1) * G3 + col);
    float fc = __builtin_bit_cast(float, pr);
    if (c == 0) c0 = fc; else if (c == 1) c1 = fc;
    else if (c == 2) c2 = fc; else c3 = fc;
  }
  float4 v; v.x = c0; v.y = c1; v.z = c2; v.w = c3;
  Wp4[s] = v;
}

__global__ __launch_bounds__(256) void k_prep(
    const void* __restrict__ W_hh, const void* __restrict__ W_ih,
    float4* __restrict__ Wp4)
{
  if (detect_f32(W_ih)) prep_body<float>((const float*)W_hh, Wp4);
  else                  prep_body<unsigned short>((const unsigned short*)W_hh, Wp4);
}

// ---------------------------------------------------------------------------
// k_proj: proj[v][j] = b_ih[j] + sum_k embed[v][k]*W_ih[k][j]. Block = one v,
// 768 threads, coalesced W_ih reads. Block 0 also converts b_hh -> f32 bb[].
// ---------------------------------------------------------------------------
template<typename T>
__device__ __forceinline__ void proj_body(const T* embed, const T* W_ih,
                                          const T* b_ih, const T* b_hh,
                                          float* proj, float* bb){
  __shared__ float s_e[HH];
  int v = blockIdx.x, j = threadIdx.x;
  if (j < HH) s_e[j] = ld1(embed, (size_t)v * HH + j);
  if (v == 0) bb[j] = ld1(b_hh, (size_t)j);
  __syncthreads();
  float acc = ld1(b_ih, (size_t)j);
  #pragma unroll 8
  for (int k = 0; k < HH; k++)
    acc += s_e[k] * ld1(W_ih, (size_t)k * G3 + j);
  proj[(size_t)v * G3 + j] = acc;
}

__global__ __launch_bounds__(768) void k_proj(
    const void* __restrict__ embed, const void* __restrict__ W_ih,
    const void* __restrict__ b_ih, const void* __restrict__ b_hh,
    float* __restrict__ proj, float* __restrict__ bb)
{
  if (detect_f32(W_ih))
    proj_body<float>((const float*)embed, (const float*)W_ih,
                     (const float*)b_ih, (const float*)b_hh, proj, bb);
  else
    proj_body<unsigned short>((const unsigned short*)embed,
                              (const unsigned short*)W_ih,
                              (const unsigned short*)b_ih,
                              (const unsigned short*)b_hh, proj, bb);
}

// ---------------------------------------------------------------------------
// k_scan: GRU scan, 512 threads (8 waves), one block per batch element.
// Thread pair (2p,2p+1) owns hidden unit p's full gate triple {r,z,n}; the
// pair splits k in halves (192 fdot2/thread, weights register-resident as
// 48 float4 = 192 VGPRs). One mov_dpp pair-swap gives BOTH lanes the three
// complete gh sums; both lanes then run the identical gate chain (same
// wave-cost as one), so no gh ever touches LDS. s_h is double-buffered ->
// exactly ONE raw (lgkmcnt-only) barrier per step.
// ---------------------------------------------------------------------------
__global__ __launch_bounds__(512, 2) void k_scan(
    const int*    __restrict__ tokens,
    const float4* __restrict__ Wp4,    // prepped weights
    const float*  __restrict__ bb,     // b_hh as f32
    const void*   __restrict__ W_ih,   // dtype detection (betas store)
    const float*  __restrict__ proj,
    _Float16*     __restrict__ outs,   // [B,T,H] f16 scratch
    void*         __restrict__ d_out_base)
{
  __shared__ float s_proj[NVOC * G3];            // 55296 B
  __shared__ int   s_tok[TT];                    //  8192 B
  __shared__ __align__(16) _Float16 s_h[2][HH];  //  1024 B double-buffered h

  const bool f32m = detect_f32(W_ih);
  const int b   = blockIdx.x;
  const int tid = threadIdx.x;     // 0..511
  const int p   = tid >> 1;        // hidden unit 0..255
  const int q   = tid & 1;         // k-half

  // stage proj (3456 float4) and tokens (512 int4)
  for (int i = tid; i < NVOC * G3 / 4; i += 512)
    ((float4*)s_proj)[i] = ((const float4*)proj)[i];
  ((int4*)s_tok)[tid] = ((const int4*)(tokens + (size_t)b * TT))[tid];

  // register-resident weights: wreg[g*16+jx]
  float4 wreg[48];
  {
    const float4* wp = Wp4 + tid;
    #pragma unroll
    for (int i = 0; i < 48; i++) wreg[i] = wp[(size_t)i * 512];
  }
  const float bhr = bb[p];
  const float bhz = bb[HH + p];
  const float bhn = bb[2*HH + p];

  if (tid < HH) s_h[0][tid] = (_Float16)0.f;
  float h_old = 0.f;

  _Float16*       orow   = outs + (size_t)b * TT * HH + p;
  unsigned short* brow_b = (unsigned short*)d_out_base + LOGITS_ELEMS
                           + (size_t)b * TT * HH + p;
  float*          brow_f = (float*)d_out_base + LOGITS_ELEMS
                           + (size_t)b * TT * HH + p;

  __syncthreads();   // staging visible (one-time full drain is fine)

  for (int t = 0; t < TT; t++) {
    // issue the next-gate LDS reads early (independent of the dot loop)
    int tok = s_tok[t];
    const float* pj = s_proj + tok * G3;
    float gir = pj[p];
    float giz = pj[HH + p];
    float gin = pj[2*HH + p];

    const int4* hb = (const int4*)(&s_h[t & 1][0]) + (q << 4);

    float r0=0.f,r1=0.f,r2=0.f,r3=0.f;
    float z0=0.f,z1=0.f,z2=0.f,z3=0.f;
    float n0=0.f,n1=0.f,n2=0.f,n3=0.f;
    #pragma unroll
    for (int jx = 0; jx < 16; jx++) {
      int4 hv = hb[jx];
      h2 x0 = bch2((unsigned)hv.x);
      h2 x1 = bch2((unsigned)hv.y);
      h2 x2 = bch2((unsigned)hv.z);
      h2 x3 = bch2((unsigned)hv.w);
      float4 wr = wreg[jx];
      float4 wz = wreg[16 + jx];
      float4 wn = wreg[32 + jx];
      r0 = FDOT2(bch2f(wr.x), x0, r0);
      r1 = FDOT2(bch2f(wr.y), x1, r1);
      r2 = FDOT2(bch2f(wr.z), x2, r2);
      r3 = FDOT2(bch2f(wr.w), x3, r3);
      z0 = FDOT2(bch2f(wz.x), x0, z0);
      z1 = FDOT2(bch2f(wz.y), x1, z1);
      z2 = FDOT2(bch2f(wz.z), x2, z2);
      z3 = FDOT2(bch2f(wz.w), x3, z3);
      n0 = FDOT2(bch2f(wn.x), x0, n0);
      n1 = FDOT2(bch2f(wn.y), x1, n1);
      n2 = FDOT2(bch2f(wn.z), x2, n2);
      n3 = FDOT2(bch2f(wn.w), x3, n3);
    }
    float ghr = (r0 + r1) + (r2 + r3);
    float ghz = (z0 + z1) + (z2 + z3);
    float ghn = (n0 + n1) + (n2 + n3);
    ghr += pair_swap(ghr);               // both lanes now hold full sums
    ghz += pair_swap(ghz);
    ghn += pair_swap(ghn);
    ghr += bhr; ghz += bhz; ghn += bhn;

    // both lanes compute the identical gate chain (no extra wave cost)
    float r = 1.f / (1.f + __expf(-(gir + ghr)));
    float z = 1.f / (1.f + __expf(-(giz + ghz)));
    float x = gin + r * ghn;
    x = fminf(fmaxf(x, -15.f), 15.f);
    float e = __expf(2.f * x);
    float n = (e - 1.f) / (e + 1.f);     // tanh
    float hn = (1.f - z) * n + z * h_old;
    h_old = hn;

    if (q == 0) {
      s_h[(t + 1) & 1][p] = (_Float16)hn;     // publish h for next step
      orow[(size_t)t * HH] = (_Float16)hn;    // f16 scratch for k_head
    } else {
      if (f32m) brow_f[(size_t)t * HH] = z;   // beta store
      else      brow_b[(size_t)t * HH] = f2bf(z);
    }
    bar_lds();   // lgkmcnt(0)+s_barrier; global stores stay in flight
  }
}

// ---------------------------------------------------------------------------
// k_head: logits = outs @ W_head + b_head.  outs is f16; W_head staged to LDS
// as packed h2 pairs (stride 129 h2 per output column -> no bank conflicts),
// inner loop is 128 fdot2.
// ---------------------------------------------------------------------------
#define WSTR 129

template<typename T>
__device__ __forceinline__ void stage_head(const T* W_head, const T* b_head,
                                           h2* s_w, float* s_b, int tid){
  for (int i = tid; i < NOUT * 128; i += 256) {
    int o = i >> 7, ip = i & 127;
    h2 pr;
    pr.x = (_Float16)ld1(W_head, (size_t)(2*ip    ) * NOUT + o);
    pr.y = (_Float16)ld1(W_head, (size_t)(2*ip + 1) * NOUT + o);
    s_w[o * WSTR + ip] = pr;
  }
  if (tid < NOUT) s_b[tid] = ld1(b_head, (size_t)tid);
}

__global__ __launch_bounds__(256) void k_head(
    const _Float16* __restrict__ outs,
    const void* __restrict__ W_head,
    const void* __restrict__ b_head,
    const void* __restrict__ W_ih,
    void* __restrict__ logits_out)
{
  __shared__ h2 s_w[NOUT * WSTR];
  __shared__ float s_b[NOUT];
  const bool f32m = detect_f32(W_ih);
  const int tid = threadIdx.x;

  if (f32m) stage_head<float>((const float*)W_head, (const float*)b_head,
                              s_w, s_b, tid);
  else      stage_head<unsigned short>((const unsigned short*)W_head,
                                       (const unsigned short*)b_head,
                                       s_w, s_b, tid);
  __syncthreads();

  size_t gid = (size_t)blockIdx.x * 256 + tid;
  if (gid >= LOGITS_ELEMS) return;
  int o = (int)(gid % NOUT);
  size_t row = gid / NOUT;

  const uint4* xp = (const uint4*)(outs + row * HH);
  const h2* wv = s_w + o * WSTR;
  float a0 = 0.f, a1 = 0.f, a2 = 0.f, a3 = 0.f;
  #pragma unroll 8
  for (int kk = 0; kk < 32; kk++) {
    uint4 u = xp[kk];
    int kb = kk * 4;
    a0 = FDOT2(bch2(u.x), wv[kb+0], a0);
    a1 = FDOT2(bch2(u.y), wv[kb+1], a1);
    a2 = FDOT2(bch2(u.z), wv[kb+2], a2);
    a3 = FDOT2(bch2(u.w), wv[kb+3], a3);
  }
  float val = ((a0 + a1) + (a2 + a3)) + s_b[o];
  if (f32m) ((float*)logits_out)[gid] = val;
  else      ((unsigned short*)logits_out)[gid] = f2bf(val);
}

// ---------------------------------------------------------------------------
extern "C" void kernel_launch(void* const* d_in, const int* in_sizes, int n_in,
                              void* d_out, int out_size, void* d_ws, size_t ws_size,
                              hipStream_t stream)
{
  // inputs: tokens, embed, W_ih, W_hh, b_ih, b_hh, W_head, b_head
  const int* tokens = (const int*)d_in[0];
  const void* embed  = d_in[1];
  const void* W_ih   = d_in[2];
  const void* W_hh   = d_in[3];
  const void* b_ih   = d_in[4];
  const void* b_hh   = d_in[5];
  const void* W_head = d_in[6];
  const void* b_head = d_in[7];

  // workspace layout (16B aligned):
  // proj: 13824 f32 = 55296 B | bb: 768 f32 = 3072 B | Wp: 24576 float4 = 393216 B | outs (f16)
  char* ws = (char*)d_ws;
  float*    proj = (float*)ws;
  float*    bb   = (float*)(ws + 55296);
  float4*   Wp4  = (float4*)(ws + 55296 + 3072);
  _Float16* outs = (_Float16*)(ws + 55296 + 3072 + 393216);

  k_prep<<<96, 256, 0, stream>>>(W_hh, W_ih, Wp4);
  k_proj<<<NVOC, G3, 0, stream>>>(embed, W_ih, b_ih, b_hh, proj, bb);
  k_scan<<<BB, 512, 0, stream>>>(tokens, Wp4, bb, W_ih, proj, outs, d_out);
  k_head<<<(int)((LOGITS_ELEMS + 255) / 256), 256, 0, stream>>>(
      outs, W_head, b_head, W_ih, d_out);
}

// Round 3
// 2617.064 us; speedup vs baseline: 1.2920x; 1.0128x over previous
//
#include <hip/hip_runtime.h>

#define BB   32
#define TT   2048
#define HH   256
#define G3   768      // 3*H
#define NVOC 18       // vocab rows (V+2)
#define NOUT 17       // head outputs (V+1)
#define LOGITS_ELEMS ((size_t)BB * TT * NOUT)

typedef _Float16 h2 __attribute__((ext_vector_type(2)));

__device__ __forceinline__ float bf1(unsigned short u){
  union{unsigned int i; float f;} v; v.i = ((unsigned int)u) << 16; return v.f;
}
__device__ __forceinline__ unsigned short f2bf(float f){
  union{float f; unsigned int i;} v; v.f = f;
  unsigned int lsb = (v.i >> 16) & 1u;
  v.i += 0x7fffu + lsb;               // round-to-nearest-even
  return (unsigned short)(v.i >> 16);
}

__device__ __forceinline__ float ld1(const float* p, size_t i){ return p[i]; }
__device__ __forceinline__ float ld1(const unsigned short* p, size_t i){ return bf1(p[i]); }

// Device-side dtype detection: W_ih ~ uniform(-1/16,1/16). If the buffer is
// f32, low-half words decode as bf16 with random exponents -> some |v|>0.25.
__device__ __forceinline__ bool detect_f32(const void* W_ih_raw){
  const unsigned short* u = (const unsigned short*)W_ih_raw;
  bool big = false;
  #pragma unroll
  for (int i = 0; i < 64; i++){
    float v = bf1(u[i]);
    big |= !(v >= -0.25f && v <= 0.25f);
  }
  return big;
}

#if __has_builtin(__builtin_amdgcn_fdot2)
#define FDOT2(a,b,c) __builtin_amdgcn_fdot2((a),(b),(c),false)
#else
#define FDOT2(a,b,c) ((c) + (float)(a).x*(float)(b).x + (float)(a).y*(float)(b).y)
#endif

__device__ __forceinline__ h2 bch2(unsigned int u){ return __builtin_bit_cast(h2, u); }
__device__ __forceinline__ h2 bch2f(float f){ return __builtin_bit_cast(h2, f); }

// DPP quad shuffles (pure VALU, no LDS round-trip)
__device__ __forceinline__ float dppB1(float v){    // quad_perm(1,0,3,2): xor1
  int i = __builtin_bit_cast(int, v);
  i = __builtin_amdgcn_mov_dpp(i, 0xB1, 0xF, 0xF, true);
  return __builtin_bit_cast(float, i);
}
__device__ __forceinline__ float dpp4E(float v){    // quad_perm(2,3,0,1): xor2
  int i = __builtin_bit_cast(int, v);
  i = __builtin_amdgcn_mov_dpp(i, 0x4E, 0xF, 0xF, true);
  return __builtin_bit_cast(float, i);
}

// raw barrier: LDS-visibility only. Skips __syncthreads()'s vmcnt(0) drain so
// per-step global stores (outs/betas, never read back in-kernel) stay
// fire-and-forget instead of stalling every iteration.
__device__ __forceinline__ void bar_lds(){
  asm volatile("s_waitcnt lgkmcnt(0)\n\ts_barrier" ::: "memory");
}

// ---------------------------------------------------------------------------
// k_prep: pack W_hh for k_scan's quad-ownership layout.
// k_scan thread tid (a=tid>>2, lq=tid&3) owns hidden-unit pair {2a, 2a+1}
// for all 3 gates, k-range [64*lq, 64*lq+64).
// Weight reg (gi, jx), gi = 2*gate + i (i = unit sub-index), jx = 0..7:
//   float4 = 4 h2 k-pairs; pair c = ( W_hh[k0+2c][col], W_hh[k0+2c+1][col] ),
//   k0 = 64*lq + 8*jx, col = 256*gate + 2a + i.
// Flat: Wp4[(gi*8 + jx)*512 + tid]; prep thread s (96x256 grid) writes Wp4[s].
// ---------------------------------------------------------------------------
template<typename T>
__device__ __forceinline__ void prep_body(const T* W_hh, float4* Wp4){
  int s   = blockIdx.x * 256 + threadIdx.x;    // 0..24575
  int tid = s & 511;
  int r9  = s >> 9;                            // 0..47
  int jx  = r9 & 7, gi = r9 >> 3;              // gi 0..5
  int g   = gi >> 1, ii = gi & 1;
  int a   = tid >> 2, lq = tid & 3;
  int col = (g << 8) + (a << 1) + ii;
  int k0  = (lq << 6) + (jx << 3);
  float c0, c1, c2, c3;
  #pragma unroll
  for (int c = 0; c < 4; c++){
    h2 pr;
    pr.x = (_Float16)ld1(W_hh, (size_t)(k0 + 2*c    ) * G3 + col);
    pr.y = (_Float16)ld1(W_hh, (size_t)(k0 + 2*c + 1) * G3 + col);
    float fc = __builtin_bit_cast(float, pr);
    if (c == 0) c0 = fc; else if (c == 1) c1 = fc;
    else if (c == 2) c2 = fc; else c3 = fc;
  }
  float4 v; v.x = c0; v.y = c1; v.z = c2; v.w = c3;
  Wp4[s] = v;
}

__global__ __launch_bounds__(256) void k_prep(
    const void* __restrict__ W_hh, const void* __restrict__ W_ih,
    float4* __restrict__ Wp4)
{
  if (detect_f32(W_ih)) prep_body<float>((const float*)W_hh, Wp4);
  else                  prep_body<unsigned short>((const unsigned short*)W_hh, Wp4);
}

// ---------------------------------------------------------------------------
// k_proj: proj[v][j] = b_ih[j] + sum_k embed[v][k]*W_ih[k][j]. Block = one v,
// 768 threads, coalesced W_ih reads. Block 0 also converts b_hh -> f32 bb[].
// ---------------------------------------------------------------------------
template<typename T>
__device__ __forceinline__ void proj_body(const T* embed, const T* W_ih,
                                          const T* b_ih, const T* b_hh,
                                          float* proj, float* bb){
  __shared__ float s_e[HH];
  int v = blockIdx.x, j = threadIdx.x;
  if (j < HH) s_e[j] = ld1(embed, (size_t)v * HH + j);
  if (v == 0) bb[j] = ld1(b_hh, (size_t)j);
  __syncthreads();
  float acc = ld1(b_ih, (size_t)j);
  #pragma unroll 8
  for (int k = 0; k < HH; k++)
    acc += s_e[k] * ld1(W_ih, (size_t)k * G3 + j);
  proj[(size_t)v * G3 + j] = acc;
}

__global__ __launch_bounds__(768) void k_proj(
    const void* __restrict__ embed, const void* __restrict__ W_ih,
    const void* __restrict__ b_ih, const void* __restrict__ b_hh,
    float* __restrict__ proj, float* __restrict__ bb)
{
  if (detect_f32(W_ih))
    proj_body<float>((const float*)embed, (const float*)W_ih,
                     (const float*)b_ih, (const float*)b_hh, proj, bb);
  else
    proj_body<unsigned short>((const unsigned short*)embed,
                              (const unsigned short*)W_ih,
                              (const unsigned short*)b_ih,
                              (const unsigned short*)b_hh, proj, bb);
}

// ---------------------------------------------------------------------------
// k_scan: GRU scan, 512 threads (8 waves), one block per batch element.
// Quad (lanes 4a..4a+3) owns hidden-unit pair {2a,2a+1}; lane lq covers
// k in [64lq, 64lq+64). 192 fdot2/thread; weights held in 48 INDIVIDUALLY
// NAMED float4 (192 VGPRs) -- no array, no alloca, nothing for SROA to punt
// on (v0/v2 used arrays; compiler left them in memory -> per-step reloads).
// Quad DPP reduction; gate chain once per lane for its selected unit; one
// lgkm-only barrier per step; s_h double-buffered + XOR line-swizzled so the
// 4 k-quarter lines of each b128 read hit disjoint banks.
// ---------------------------------------------------------------------------

// X-macro over the 48 weight registers
#define FORJX(M, g, i, base) \
  M(g,i,0,(base)+0) M(g,i,1,(base)+1) M(g,i,2,(base)+2) M(g,i,3,(base)+3) \
  M(g,i,4,(base)+4) M(g,i,5,(base)+5) M(g,i,6,(base)+6) M(g,i,7,(base)+7)
#define FORALLW(M) \
  FORJX(M,r,0,0)  FORJX(M,r,1,8)  FORJX(M,z,0,16) \
  FORJX(M,z,1,24) FORJX(M,n,0,32) FORJX(M,n,1,40)

#define DECLW(g,i,jx,idx) float4 w_##g##i##_##jx = wp[(idx)*512];

#define DOTJ(jx) { \
  int4 hv = hp[hix##jx]; \
  h2 x0 = bch2((unsigned)hv.x), x1 = bch2((unsigned)hv.y), \
     x2 = bch2((unsigned)hv.z), x3 = bch2((unsigned)hv.w); \
  ar0 = FDOT2(bch2f(w_r0_##jx.x), x0, ar0); \
  ar1 = FDOT2(bch2f(w_r1_##jx.x), x0, ar1); \
  az0 = FDOT2(bch2f(w_z0_##jx.x), x0, az0); \
  az1 = FDOT2(bch2f(w_z1_##jx.x), x0, az1); \
  an0 = FDOT2(bch2f(w_n0_##jx.x), x0, an0); \
  an1 = FDOT2(bch2f(w_n1_##jx.x), x0, an1); \
  ar0 = FDOT2(bch2f(w_r0_##jx.y), x1, ar0); \
  ar1 = FDOT2(bch2f(w_r1_##jx.y), x1, ar1); \
  az0 = FDOT2(bch2f(w_z0_##jx.y), x1, az0); \
  az1 = FDOT2(bch2f(w_z1_##jx.y), x1, az1); \
  an0 = FDOT2(bch2f(w_n0_##jx.y), x1, an0); \
  an1 = FDOT2(bch2f(w_n1_##jx.y), x1, an1); \
  ar0 = FDOT2(bch2f(w_r0_##jx.z), x2, ar0); \
  ar1 = FDOT2(bch2f(w_r1_##jx.z), x2, ar1); \
  az0 = FDOT2(bch2f(w_z0_##jx.z), x2, az0); \
  az1 = FDOT2(bch2f(w_z1_##jx.z), x2, az1); \
  an0 = FDOT2(bch2f(w_n0_##jx.z), x2, an0); \
  an1 = FDOT2(bch2f(w_n1_##jx.z), x2, an1); \
  ar0 = FDOT2(bch2f(w_r0_##jx.w), x3, ar0); \
  ar1 = FDOT2(bch2f(w_r1_##jx.w), x3, ar1); \
  az0 = FDOT2(bch2f(w_z0_##jx.w), x3, az0); \
  az1 = FDOT2(bch2f(w_z1_##jx.w), x3, az1); \
  an0 = FDOT2(bch2f(w_n0_##jx.w), x3, an0); \
  an1 = FDOT2(bch2f(w_n1_##jx.w), x3, an1); }

__global__ __launch_bounds__(512, 2) void k_scan(
    const int*    __restrict__ tokens,
    const float4* __restrict__ Wp4,    // prepped weights
    const float*  __restrict__ bb,     // b_hh as f32
    const void*   __restrict__ W_ih,   // dtype detection (betas store)
    const float*  __restrict__ proj,
    _Float16*     __restrict__ outs,   // [B,T,H] f16 scratch
    void*         __restrict__ d_out_base)
{
  __shared__ float s_proj[NVOC * G3];            // 55296 B
  __shared__ int   s_tok[TT];                    //  8192 B
  __shared__ __align__(16) _Float16 s_h[2][HH];  //  1024 B dbuf h (swizzled)

  const bool f32m = detect_f32(W_ih);
  const int b   = blockIdx.x;
  const int tid = threadIdx.x;     // 0..511
  const int a   = tid >> 2;        // unit-pair 0..127 -> units {2a, 2a+1}
  const int lq  = tid & 3;         // k-quarter
  const int sel = lq >> 1;         // this lane's gate unit: 2a + sel
  const int u   = 2*a + sel;

  // stage proj (3456 float4) and tokens (512 int4); zero both h buffers
  for (int i = tid; i < NVOC * G3 / 4; i += 512)
    ((float4*)s_proj)[i] = ((const float4*)proj)[i];
  ((int4*)s_tok)[tid] = ((const int4*)(tokens + (size_t)b * TT))[tid];
  if (tid < 256) ((int*)s_h)[tid] = 0;

  // 48 named weight registers (192 VGPRs) -- forced residency
  const float4* wp = Wp4 + tid;
  FORALLW(DECLW)

  // biases for this lane's unit
  const float bhr = bb[u];
  const float bhz = bb[HH + u];
  const float bhn = bb[2*HH + u];

  // swizzle: logical 16B line L (of 32 per buffer) lives at physical line
  // (L&24) | ((L&7) ^ (L>>3)).  Reader line for (lq,jx): L = 8lq+jx ->
  // phys = 8lq | (jx^lq)  (disjoint bank-quads across lq).  Writer dword a:
  int pa;
  {
    int Ld = a >> 2, md = a >> 5;
    pa = (((Ld & 24) | ((Ld & 7) ^ md)) << 2) | (a & 3);
  }
  const int hb = lq << 3;
  const int hix0 = hb | (0 ^ lq), hix1 = hb | (1 ^ lq), hix2 = hb | (2 ^ lq),
            hix3 = hb | (3 ^ lq), hix4 = hb | (4 ^ lq), hix5 = hb | (5 ^ lq),
            hix6 = hb | (6 ^ lq), hix7 = hb | (7 ^ lq);

  float h_old = 0.f;               // h[u]

  unsigned* orow_u = (unsigned*)outs + (((size_t)b * TT * HH) >> 1) + a;
  unsigned* brow_u = (unsigned*)((unsigned short*)d_out_base + LOGITS_ELEMS)
                     + (((size_t)b * TT * HH) >> 1) + a;
  float2*   brow_f = (float2*)((float*)d_out_base + LOGITS_ELEMS)
                     + (((size_t)b * TT * HH) >> 1) + a;

  __syncthreads();   // staging + weight loads settled (one-time full drain)

  for (int t = 0; t < TT; t++) {
    int tok = s_tok[t];
    const float* pj = s_proj + tok * G3;
    float gir = pj[u];
    float giz = pj[HH + u];
    float gin = pj[2*HH + u];

    const int4* hp = (const int4*)(&s_h[t & 1][0]);

    float ar0=0.f, ar1=0.f, az0=0.f, az1=0.f, an0=0.f, an1=0.f;
    DOTJ(0) DOTJ(1) DOTJ(2) DOTJ(3) DOTJ(4) DOTJ(5) DOTJ(6) DOTJ(7)

    // own-unit / other-unit partial selection, then quad reduction:
    // step 1 (xor2 via 0x4E): my k-quarter + partner's k-quarter of MY unit
    // step 2 (xor1 via 0xB1): combine the two k-halves
    float pr = sel ? ar1 : ar0,  qr = sel ? ar0 : ar1;
    float pz = sel ? az1 : az0,  qz = sel ? az0 : az1;
    float pn = sel ? an1 : an0,  qn = sel ? an0 : an1;
    pr += dpp4E(qr);  pz += dpp4E(qz);  pn += dpp4E(qn);
    pr += dppB1(pr);  pz += dppB1(pz);  pn += dppB1(pn);

    // gate chain, once per lane for unit u
    float r = 1.f / (1.f + __expf(-(gir + pr + bhr)));
    float z = 1.f / (1.f + __expf(-(giz + pz + bhz)));
    float x = gin + r * (pn + bhn);
    x = fminf(fmaxf(x, -15.f), 15.f);
    float e = __expf(2.f * x);
    float n = (e - 1.f) / (e + 1.f);     // tanh
    float hn = (1.f - z) * n + z * h_old;
    h_old = hn;

    // cross-lane partner values for packed stores
    float hn_o = dpp4E(hn);              // other unit's hn
    float z_o  = dpp4E(z);               // other unit's z

    if (lq == 0) {                       // publish h pair {u0,u1} (swizzled)
      h2 ph; ph.x = (_Float16)hn; ph.y = (_Float16)hn_o;
      ((unsigned*)(&s_h[(t + 1) & 1][0]))[pa] = __builtin_bit_cast(unsigned, ph);
    } else if (lq == 2) {                // outs f16 pair {u0,u1}
      h2 po; po.x = (_Float16)hn_o; po.y = (_Float16)hn;
      orow_u[(size_t)t * (HH/2)] = __builtin_bit_cast(unsigned, po);
    } else if (lq == 1) {                // beta pair {u0,u1}
      if (f32m) { float2 fz; fz.x = z; fz.y = z_o;
                  brow_f[(size_t)t * (HH/2)] = fz; }
      else      { unsigned pz2 = (unsigned)f2bf(z) | ((unsigned)f2bf(z_o) << 16);
                  brow_u[(size_t)t * (HH/2)] = pz2; }
    }
    bar_lds();   // lgkmcnt(0)+s_barrier; global stores stay in flight
  }
}

// ---------------------------------------------------------------------------
// k_head: logits = outs @ W_head + b_head.  outs is f16; W_head staged to LDS
// as packed h2 pairs (stride 129 h2 per output column -> no bank conflicts),
// inner loop is 128 fdot2.
// ---------------------------------------------------------------------------
#define WSTR 129

template<typename T>
__device__ __forceinline__ void stage_head(const T* W_head, const T* b_head,
                                           h2* s_w, float* s_b, int tid){
  for (int i = tid; i < NOUT * 128; i += 256) {
    int o = i >> 7, ip = i & 127;
    h2 pr;
    pr.x = (_Float16)ld1(W_head, (size_t)(2*ip    ) * NOUT + o);
    pr.y = (_Float16)ld1(W_head, (size_t)(2*ip + 1) * NOUT + o);
    s_w[o * WSTR + ip] = pr;
  }
  if (tid < NOUT) s_b[tid] = ld1(b_head, (size_t)tid);
}

__global__ __launch_bounds__(256) void k_head(
    const _Float16* __restrict__ outs,
    const void* __restrict__ W_head,
    const void* __restrict__ b_head,
    const void* __restrict__ W_ih,
    void* __restrict__ logits_out)
{
  __shared__ h2 s_w[NOUT * WSTR];
  __shared__ float s_b[NOUT];
  const bool f32m = detect_f32(W_ih);
  const int tid = threadIdx.x;

  if (f32m) stage_head<float>((const float*)W_head, (const float*)b_head,
                              s_w, s_b, tid);
  else      stage_head<unsigned short>((const unsigned short*)W_head,
                                       (const unsigned short*)b_head,
                                       s_w, s_b, tid);
  __syncthreads();

  size_t gid = (size_t)blockIdx.x * 256 + tid;
  if (gid >= LOGITS_ELEMS) return;
  int o = (int)(gid % NOUT);
  size_t row = gid / NOUT;

  const uint4* xp = (const uint4*)(outs + row * HH);
  const h2* wv = s_w + o * WSTR;
  float a0 = 0.f, a1 = 0.f, a2 = 0.f, a3 = 0.f;
  #pragma unroll 8
  for (int kk = 0; kk < 32; kk++) {
    uint4 u = xp[kk];
    int kb = kk * 4;
    a0 = FDOT2(bch2(u.x), wv[kb+0], a0);
    a1 = FDOT2(bch2(u.y), wv[kb+1], a1);
    a2 = FDOT2(bch2(u.z), wv[kb+2], a2);
    a3 = FDOT2(bch2(u.w), wv[kb+3], a3);
  }
  float val = ((a0 + a1) + (a2 + a3)) + s_b[o];
  if (f32m) ((float*)logits_out)[gid] = val;
  else      ((unsigned short*)logits_out)[gid] = f2bf(val);
}

// ---------------------------------------------------------------------------
extern "C" void kernel_launch(void* const* d_in, const int* in_sizes, int n_in,
                              void* d_out, int out_size, void* d_ws, size_t ws_size,
                              hipStream_t stream)
{
  // inputs: tokens, embed, W_ih, W_hh, b_ih, b_hh, W_head, b_head
  const int* tokens = (const int*)d_in[0];
  const void* embed  = d_in[1];
  const void* W_ih   = d_in[2];
  const void* W_hh   = d_in[3];
  const void* b_ih   = d_in[4];
  const void* b_hh   = d_in[5];
  const void* W_head = d_in[6];
  const void* b_head = d_in[7];

  // workspace layout (16B aligned):
  // proj: 13824 f32 = 55296 B | bb: 768 f32 = 3072 B | Wp: 24576 float4 = 393216 B | outs (f16)
  char* ws = (char*)d_ws;
  float*    proj = (float*)ws;
  float*    bb   = (float*)(ws + 55296);
  float4*   Wp4  = (float4*)(ws + 55296 + 3072);
  _Float16* outs = (_Float16*)(ws + 55296 + 3072 + 393216);

  k_prep<<<96, 256, 0, stream>>>(W_hh, W_ih, Wp4);
  k_proj<<<NVOC, G3, 0, stream>>>(embed, W_ih, b_ih, b_hh, proj, bb);
  k_scan<<<BB, 512, 0, stream>>>(tokens, Wp4, bb, W_ih, proj, outs, d_out);
  k_head<<<(int)((LOGITS_ELEMS + 255) / 256), 256, 0, stream>>>(
      outs, W_head, b_head, W_ih, d_out);
}